// Round 15
// baseline (59.886 us; speedup 1.0000x reference)
//
#include <hip/hip_runtime.h>
#include <math.h>

#define KP    125       // 5*5*5 filter taps
#define NQE   252       // 6*6*7 quad entries (8B each) per frame buffer
#define WPB   4         // waves per block
#define NF    8         // filters per wave

typedef _Float16 half_t;
typedef half_t h2 __attribute__((ext_vector_type(2)));
typedef __fp16 fp16x2 __attribute__((ext_vector_type(2)));

static __device__ __forceinline__ h2 h2fma(h2 a, h2 b, h2 c) {
    return __builtin_elementwise_fma(a, b, c);
}
static __device__ __forceinline__ unsigned int cvt_pk_u(float a, float b) {
    fp16x2 t = __builtin_amdgcn_cvt_pkrtz(a, b);   // v_cvt_pkrtz_f16_f32
    return __builtin_bit_cast(unsigned int, t);
}
static __device__ __forceinline__ h2 cvt_pk(float a, float b) {
    fp16x2 t = __builtin_amdgcn_cvt_pkrtz(a, b);
    return __builtin_bit_cast(h2, t);
}
static __device__ __forceinline__ h2 bch2(unsigned int u) {
    return __builtin_bit_cast(h2, u);
}
static __device__ __forceinline__ float rdlane(float v, int k) {
    return __builtin_bit_cast(float,
        __builtin_amdgcn_readlane(__builtin_bit_cast(int, v), k));
}

// ---------- Fused: in-wave Rodrigues + mirror-paired quad-pack sampling ----------
__global__ __launch_bounds__(WPB * 64) void fastrot_kernel(
    const float* __restrict__ vol,      // N*125
    const float* __restrict__ theta_v,  // N*3
    const float* __restrict__ theta,    // N
    float* __restrict__ out)            // N*125
{
    // Quad entry (x,y,z) = half4 {F(x,y,z), F(x+1,y,z), F(x,y+1,z), F(x+1,y+1,z)}
    // at index z*36 + y*6 + x  (x,y in [0,5], z in [0,6]); F = 7^3 zero-ring
    // frame with data 5^3 at +1/axis. One sample = ds_read2_b64 (z0, z0+1).
    // Even/odd buffers decouple gather(k) from scatter(k+1).
    __shared__ __align__(16) uint2 pad[WPB][2][NQE];

    const int lane = threadIdx.x & 63;
    const int ws   = __builtin_amdgcn_readfirstlane(threadIdx.x >> 6);
    const long long base = ((long long)blockIdx.x * WPB + ws) * NF;

    // ---- zero-fill both frame buffers once per wave (252 uint4 total) ----
    uint4* fp4 = (uint4*)(&pad[ws][0][0]);
    const uint4 z4 = make_uint4(0u, 0u, 0u, 0u);
    fp4[lane]       = z4;
    fp4[lane + 64]  = z4;
    fp4[lane + 128] = z4;
    if (lane < 60) fp4[lane + 192] = z4;

    // ---- lane-parallel Rodrigues: lane computes R for filter base+(lane&7) ----
    float r00, r01, r02, r10, r11, r12, r20, r21, r22;
    {
        const long long m = base + (lane & (NF - 1));
        const float ax = theta_v[m * 3 + 0];
        const float ay = theta_v[m * 3 + 1];
        const float az = theta_v[m * 3 + 2];
        const float th = theta[m];
        const float d2  = ax * ax + ay * ay + az * az;
        const float inv = rsqrtf(fmaxf(d2, 1e-24f));
        const float vx = ax * inv, vy = ay * inv, vz = az * inv;
        float s, cth;
        __sincosf(th, &s, &cth);
        const float c = 1.0f - cth;
        r00 = 1.0f - c * (vy * vy + vz * vz);
        r01 = -s * vz + c * (vx * vy);
        r02 =  s * vy + c * (vx * vz);
        r10 =  s * vz + c * (vx * vy);
        r11 = 1.0f - c * (vx * vx + vz * vz);
        r12 = -s * vx + c * (vy * vz);
        r20 = -s * vy + c * (vx * vz);
        r21 =  s * vx + c * (vy * vz);
        r22 = 1.0f - c * (vx * vx + vy * vy);
    }

    // ---- per-wave-constant decomposition; mirror pair p1 = 124 - p0 ----
    const int p0 = lane;                 // 0..63
    const int p1 = 124 - lane;           // 124..61 (61-63 duplicated, benign)
    const int i0 = (p0 * 41) >> 10;
    const int q0 = (p0 * 205) >> 10;
    const int j0 = q0 - i0 * 5;
    const int l0 = p0 - q0 * 5;
    const int i1 = 4 - i0, j1 = 4 - j0, l1 = 4 - l0;
    const float Bi0 = (float)(i0 - 2), Bj0 = (float)(j0 - 2), Bl0 = (float)(l0 - 2);

    // quad-entry addresses (filter-invariant): main, x=0 border, y=0 border, corner
    const int e0m = (i0 + 1) * 36 + (j0 + 1) * 6 + (l0 + 1);
    const int e0x = (i0 + 1) * 36 + (j0 + 1) * 6;
    const int e0y = (i0 + 1) * 36 + (l0 + 1);
    const int e0c = (i0 + 1) * 36;
    const int e1m = (i1 + 1) * 36 + (j1 + 1) * 6 + (l1 + 1);
    const int e1x = (i1 + 1) * 36 + (j1 + 1) * 6;
    const int e1y = (i1 + 1) * 36 + (l1 + 1);
    const int e1c = (i1 + 1) * 36;

    // ---- stage all filters as packed quad halves (4 dwords/filter) ----
    // sq.x = {v(i,j,l), v(i,j,l+1)}  sq.y = {v(i,j+1,l), v(i,j+1,l+1)} (masked)
    unsigned int s0x[NF], s0y[NF], s1x[NF], s1y[NF];
    const int a1b = (p1 + 1 > 124) ? 124 : p1 + 1;   // clamped (masked lanes only)
    const int a1c = (p1 + 5 > 124) ? 124 : p1 + 5;
    const int a1d = (p1 + 6 > 124) ? 124 : p1 + 6;
#pragma unroll
    for (int k = 0; k < NF; ++k) {
        const float* vn = vol + (base + k) * KP;
        float a = vn[p0];                      // p0 side: p0+6 <= 69, in-bounds
        float b = vn[p0 + 1];
        float c = vn[p0 + 5];
        float d = vn[p0 + 6];
        if (l0 == 4) { b = 0.0f; d = 0.0f; }
        if (j0 == 4) { c = 0.0f; d = 0.0f; }
        s0x[k] = cvt_pk_u(a, b);
        s0y[k] = cvt_pk_u(c, d);

        float a1 = vn[p1];
        float b1 = vn[a1b];
        float c1 = vn[a1c];
        float d1 = vn[a1d];
        if (l1 == 4) { b1 = 0.0f; d1 = 0.0f; }
        if (j1 == 4) { c1 = 0.0f; d1 = 0.0f; }
        s1x[k] = cvt_pk_u(a1, b1);
        s1y[k] = cvt_pk_u(c1, d1);
    }

    // ---- per-filter: broadcast R, scatter quads, sample mirror pair, store ----
#pragma unroll
    for (int k = 0; k < NF; ++k) {
        uint2* buf = &pad[ws][k & 1][0];

        const float R00 = rdlane(r00, k), R01 = rdlane(r01, k), R02 = rdlane(r02, k);
        const float R10 = rdlane(r10, k), R11 = rdlane(r11, k), R12 = rdlane(r12, k);
        const float R20 = rdlane(r20, k), R21 = rdlane(r21, k), R22 = rdlane(r22, k);

        // scatter quads; borders are shifts of staged dwords
        buf[e0m] = make_uint2(s0x[k], s0y[k]);
        if (l0 == 0) buf[e0x] = make_uint2(s0x[k] << 16, s0y[k] << 16); // {0,fv,0,ny}
        if (j0 == 0) buf[e0y] = make_uint2(0u, s0x[k]);                 // {0,0,fv,nx}
        if (l0 == 0 && j0 == 0) buf[e0c] = make_uint2(0u, s0x[k] << 16);// {0,0,0,fv}
        buf[e1m] = make_uint2(s1x[k], s1y[k]);
        if (l1 == 0) buf[e1x] = make_uint2(s1x[k] << 16, s1y[k] << 16);
        if (j1 == 0) buf[e1y] = make_uint2(0u, s1x[k]);
        if (l1 == 0 && j1 == 0) buf[e1c] = make_uint2(0u, s1x[k] << 16);

        float* on = out + (base + k) * KP;

        // raw frame coords for p0 (9 fma); p1's are the mirror 6 - raw.
        const float xr = fmaf(Bi0, R00, fmaf(Bj0, R10, fmaf(Bl0, R20, 3.0f)));
        const float yr = fmaf(Bi0, R01, fmaf(Bj0, R11, fmaf(Bl0, R21, 3.0f)));
        const float zr = fmaf(Bi0, R02, fmaf(Bj0, R12, fmaf(Bl0, R22, 3.0f)));

        // clamp to [0, 5.99994] == zero-pad sampling in the 7-frame
        auto gather = [&](float xf, float yf, float zf) -> float {
            xf = fminf(fmaxf(xf, 0.0f), 5.99993896f);
            yf = fminf(fmaxf(yf, 0.0f), 5.99993896f);
            zf = fminf(fmaxf(zf, 0.0f), 5.99993896f);
            const int x0 = (int)xf, y0 = (int)yf, z0 = (int)zf;
            const float wx = __builtin_amdgcn_fractf(xf);
            const float wy = __builtin_amdgcn_fractf(yf);
            const float wz = __builtin_amdgcn_fractf(zf);
            const int ci8 = z0 * 36 + y0 * 6 + x0;       // in [0, 215]

            // one ds_read2_b64: quads at z0 and z0+1
            const uint2 H0 = buf[ci8];
            const uint2 H1 = buf[ci8 + 36];
            const h2 lo0 = bch2(H0.x), hi0 = bch2(H0.y);
            const h2 lo1 = bch2(H1.x), hi1 = bch2(H1.y);

            const h2 wzh = cvt_pk(wz, wz);
            const h2 wyh = cvt_pk(wy, wy);
            const h2 E  = h2fma(wzh, lo1 - lo0, lo0);    // y0 row @ z-lerped
            const h2 Fh = h2fma(wzh, hi1 - hi0, hi0);    // y0+1 row
            const h2 G  = h2fma(wyh, Fh - E, E);         // {g(x0), g(x0+1)}
            const float g0 = (float)G.x;
            const float g1 = (float)G.y;
            return fmaf(wx, g1 - g0, g0);
        };

        on[p0] = gather(xr, yr, zr);
        on[p1] = gather(6.0f - xr, 6.0f - yr, 6.0f - zr);
    }
}

extern "C" void kernel_launch(void* const* d_in, const int* in_sizes, int n_in,
                              void* d_out, int out_size, void* d_ws, size_t ws_size,
                              hipStream_t stream) {
    const float* vol     = (const float*)d_in[0];
    const float* theta_v = (const float*)d_in[1];
    const float* theta   = (const float*)d_in[2];
    float* out           = (float*)d_out;

    const int N = in_sizes[2];          // 262144, divisible by WPB*NF = 32

    fastrot_kernel<<<N / (WPB * NF), WPB * 64, 0, stream>>>(vol, theta_v, theta, out);
}

// Round 16
// 53.293 us; speedup vs baseline: 1.1237x; 1.1237x over previous
//
#include <hip/hip_runtime.h>
#include <math.h>

#define KP    125       // 5*5*5 filter taps
#define VOL7P 344       // 7*7*7 = 343 pair-entries (dwords), rounded to /4
#define WPB   4         // waves per block
#define NF    8         // filters per wave

typedef _Float16 half_t;
typedef half_t h2 __attribute__((ext_vector_type(2)));
typedef __fp16 fp16x2 __attribute__((ext_vector_type(2)));

static __device__ __forceinline__ h2 h2fma(h2 a, h2 b, h2 c) {
    return __builtin_elementwise_fma(a, b, c);
}
static __device__ __forceinline__ h2 cvt_pk(float a, float b) {
    fp16x2 t = __builtin_amdgcn_cvt_pkrtz(a, b);   // v_cvt_pkrtz_f16_f32
    return __builtin_bit_cast(h2, t);
}
static __device__ __forceinline__ float rdlane(float v, int k) {
    return __builtin_bit_cast(float,
        __builtin_amdgcn_readlane(__builtin_bit_cast(int, v), k));
}

// ---------- Fused: in-wave Rodrigues + mirror-paired sampling (R14 best) ----------
__global__ __launch_bounds__(WPB * 64) void fastrot_kernel(
    const float* __restrict__ vol,      // N*125
    const float* __restrict__ theta_v,  // N*3
    const float* __restrict__ theta,    // N
    float* __restrict__ out)            // N*125
{
    // pad entry (z,y,x) = half2 {F(x), F(x+1)}, 7^3 zero-ring frame,
    // data 5^3 at +1 per axis. Even/odd buffers decouple gather(k) from
    // scatter(k+1) so the scheduler can overlap filters.
    __shared__ __align__(16) unsigned int pad[WPB][2][VOL7P];

    const int lane = threadIdx.x & 63;
    const int ws   = __builtin_amdgcn_readfirstlane(threadIdx.x >> 6);
    const long long base = ((long long)blockIdx.x * WPB + ws) * NF;

    // ---- zero-fill both frame buffers once per wave ----
    uint4* f0 = (uint4*)(&pad[ws][0][0]);
    uint4* f1 = (uint4*)(&pad[ws][1][0]);
    const uint4 z4 = make_uint4(0u, 0u, 0u, 0u);
    f0[lane] = z4;
    f1[lane] = z4;
    if (lane < (VOL7P / 4 - 64)) { f0[lane + 64] = z4; f1[lane + 64] = z4; }

    // ---- lane-parallel Rodrigues: lane computes R for filter base+(lane&7) ----
    float r00, r01, r02, r10, r11, r12, r20, r21, r22;
    {
        const long long m = base + (lane & (NF - 1));
        const float ax = theta_v[m * 3 + 0];
        const float ay = theta_v[m * 3 + 1];
        const float az = theta_v[m * 3 + 2];
        const float th = theta[m];
        const float d2  = ax * ax + ay * ay + az * az;
        const float inv = rsqrtf(fmaxf(d2, 1e-24f));
        const float vx = ax * inv, vy = ay * inv, vz = az * inv;
        float s, cth;
        __sincosf(th, &s, &cth);
        const float c = 1.0f - cth;
        r00 = 1.0f - c * (vy * vy + vz * vz);
        r01 = -s * vz + c * (vx * vy);
        r02 =  s * vy + c * (vx * vz);
        r10 =  s * vz + c * (vx * vy);
        r11 = 1.0f - c * (vx * vx + vz * vz);
        r12 = -s * vx + c * (vy * vz);
        r20 = -s * vy + c * (vx * vz);
        r21 =  s * vx + c * (vy * vz);
        r22 = 1.0f - c * (vx * vx + vy * vy);
    }

    // ---- per-wave-constant decomposition; mirror pair p1 = 124 - p0 ----
    const int p0 = lane;                 // 0..63
    const int p1 = 124 - lane;           // 124..61 (61-63 duplicated, benign)
    const int i0 = (p0 * 41) >> 10;
    const int q0 = (p0 * 205) >> 10;
    const int j0 = q0 - i0 * 5;
    const int l0 = p0 - q0 * 5;
    const int i1 = 4 - i0, j1 = 4 - j0, l1 = 4 - l0;
    const int e0 = i0 * 49 + j0 * 7 + l0 + 57;
    const int e1 = i1 * 49 + j1 * 7 + l1 + 57;
    const float Bi0 = (float)(i0 - 2), Bj0 = (float)(j0 - 2), Bl0 = (float)(l0 - 2);

    // ---- stage all filters' values (compiler schedules the loads) ----
    float fv0[NF], fv1[NF], nx0[NF], nx1[NF];
#pragma unroll
    for (int k = 0; k < NF; ++k) {
        const float* vn = vol + (base + k) * KP;
        fv0[k] = vn[p0];
        fv1[k] = vn[p1];
        nx0[k] = (l0 < 4) ? vn[p0 + 1] : 0.0f;
        nx1[k] = (l1 < 4) ? vn[p1 + 1] : 0.0f;   // l1<4 -> p1+1 <= 124
    }

    // ---- per-filter: broadcast R, scatter both points, sample pair, store ----
#pragma unroll
    for (int k = 0; k < NF; ++k) {
        unsigned int* buf = &pad[ws][k & 1][0];

        const float R00 = rdlane(r00, k), R01 = rdlane(r01, k), R02 = rdlane(r02, k);
        const float R10 = rdlane(r10, k), R11 = rdlane(r11, k), R12 = rdlane(r12, k);
        const float R20 = rdlane(r20, k), R21 = rdlane(r21, k), R22 = rdlane(r22, k);

        // scatter pair entries (both points; duplicates write identical data)
        buf[e0] = __builtin_bit_cast(unsigned int, cvt_pk(fv0[k], nx0[k]));
        if (l0 == 0)
            buf[e0 - 1] = __builtin_bit_cast(unsigned int, cvt_pk(0.0f, fv0[k]));
        buf[e1] = __builtin_bit_cast(unsigned int, cvt_pk(fv1[k], nx1[k]));
        if (l1 == 0)
            buf[e1 - 1] = __builtin_bit_cast(unsigned int, cvt_pk(0.0f, fv1[k]));

        float* on = out + (base + k) * KP;

        // raw frame coords for p0 (9 fma); p1's are the mirror 6 - raw.
        const float xr = fmaf(Bi0, R00, fmaf(Bj0, R10, fmaf(Bl0, R20, 3.0f)));
        const float yr = fmaf(Bi0, R01, fmaf(Bj0, R11, fmaf(Bl0, R21, 3.0f)));
        const float zr = fmaf(Bi0, R02, fmaf(Bj0, R12, fmaf(Bl0, R22, 3.0f)));

        // clamp to [0, 5.99994] == zero-pad sampling in the 7-frame
        auto gather = [&](float xf, float yf, float zf) -> float {
            xf = fminf(fmaxf(xf, 0.0f), 5.99993896f);
            yf = fminf(fmaxf(yf, 0.0f), 5.99993896f);
            zf = fminf(fmaxf(zf, 0.0f), 5.99993896f);
            const int x0 = (int)xf, y0 = (int)yf, z0 = (int)zf;
            const float wx = __builtin_amdgcn_fractf(xf);
            const float wy = __builtin_amdgcn_fractf(yf);
            const float wz = __builtin_amdgcn_fractf(zf);
            const int ci = z0 * 49 + y0 * 7 + x0;        // in [0, 285]

            // 2x ds_read2_b32: (ci, ci+49) and (ci+7, ci+56)
            const h2 A0 = __builtin_bit_cast(h2, buf[ci]);        // (y0,z0)
            const h2 A1 = __builtin_bit_cast(h2, buf[ci + 49]);   // (y0,z1)
            const h2 B0 = __builtin_bit_cast(h2, buf[ci + 7]);    // (y1,z0)
            const h2 B1 = __builtin_bit_cast(h2, buf[ci + 56]);   // (y1,z1)

            const h2 wzh = cvt_pk(wz, wz);
            const h2 wyh = cvt_pk(wy, wy);
            const h2 E = h2fma(wzh, A1 - A0, A0);
            const h2 F = h2fma(wzh, B1 - B0, B0);
            const h2 G = h2fma(wyh, F - E, E);
            const float g0 = (float)G.x;
            const float g1 = (float)G.y;
            return fmaf(wx, g1 - g0, g0);
        };

        on[p0] = gather(xr, yr, zr);
        on[p1] = gather(6.0f - xr, 6.0f - yr, 6.0f - zr);
    }
}

extern "C" void kernel_launch(void* const* d_in, const int* in_sizes, int n_in,
                              void* d_out, int out_size, void* d_ws, size_t ws_size,
                              hipStream_t stream) {
    const float* vol     = (const float*)d_in[0];
    const float* theta_v = (const float*)d_in[1];
    const float* theta   = (const float*)d_in[2];
    float* out           = (float*)d_out;

    const int N = in_sizes[2];          // 262144, divisible by WPB*NF = 32

    fastrot_kernel<<<N / (WPB * NF), WPB * 64, 0, stream>>>(vol, theta_v, theta, out);
}